// Round 1
// 155.033 us; speedup vs baseline: 1.0229x; 1.0229x over previous
//
#include <hip/hip_runtime.h>

#define N_NODES 50000
#define N_EDGES 625000
#define DIM 128
#define CAP 64            // bucket capacity per node; max degree ~29 (Poisson 12.5)

typedef __bf16 bf16x8 __attribute__((ext_vector_type(8)));
typedef __bf16 bf16x4 __attribute__((ext_vector_type(4)));
typedef __bf16 bf16x2 __attribute__((ext_vector_type(2)));
typedef float f32x4 __attribute__((ext_vector_type(4)));

__device__ __forceinline__ float bflo(unsigned u) { return __uint_as_float(u << 16); }
__device__ __forceinline__ float bfhi(unsigned u) { return __uint_as_float(u & 0xffff0000u); }

// ===========================================================================
// K1: fused [GEMM1 | bucket-CSR fill], 512-thread blocks (unchanged this
// round — 43.8 us, atomic/latency-bound on the fill part; separate target).
// ===========================================================================
__global__ __launch_bounds__(512) void gemm1_fill_k(
    const float* __restrict__ A_f32,
    const float* __restrict__ W,
    const float* __restrict__ bias,
    __bf16* __restrict__ out_bf16,
    const int* __restrict__ src,
    const int* __restrict__ dst,
    int* __restrict__ cnt,
    int* __restrict__ bucket,
    const float* __restrict__ W_phy,
    __bf16* __restrict__ Wb,
    int gemm_blocks)
{
    const int t = threadIdx.x;

    if ((int)blockIdx.x >= gemm_blocks) {
        if ((int)blockIdx.x == gemm_blocks) {
            if (t < 16) {
                bf16x8 z = {};
                *(bf16x8*)&out_bf16[(size_t)N_NODES * DIM + t * 8] = z;
            }
            for (int i = t; i < 4096; i += 512) {
                float4 f = ((const float4*)W_phy)[i];
                bf16x4 pk = { (__bf16)f.x, (__bf16)f.y, (__bf16)f.z, (__bf16)f.w };
                *(bf16x4*)&Wb[i * 4] = pk;
            }
        }
        int idx = ((int)blockIdx.x - gemm_blocks) * 512 + t;
        if (idx < N_EDGES / 4) {
            int4 s4 = ((const int4*)src)[idx];
            int4 d4 = ((const int4*)dst)[idx];
            int p0 = atomicAdd(&cnt[d4.x], 1);
            bucket[(d4.x << 6) + p0] = s4.x;
            int p1 = atomicAdd(&cnt[d4.y], 1);
            bucket[(d4.y << 6) + p1] = s4.y;
            int p2 = atomicAdd(&cnt[d4.z], 1);
            bucket[(d4.z << 6) + p2] = s4.z;
            int p3 = atomicAdd(&cnt[d4.w], 1);
            bucket[(d4.w << 6) + p3] = s4.w;
        }
        return;
    }

    __shared__ __align__(16) __bf16 w_lds[128 * 136];   // 34.8 KB

    for (int i = t; i < 4096; i += 512) {               // 8 iters
        float4 f = ((const float4*)W)[i];
        int n = i >> 5;
        int k = (i & 31) << 2;
        bf16x4 pk = { (__bf16)f.x, (__bf16)f.y, (__bf16)f.z, (__bf16)f.w };
        *(bf16x4*)&w_lds[n * 136 + k] = pk;             // ds_write_b64
    }
    __syncthreads();

    const int wave = t >> 6;           // 0..7
    const int lane = t & 63;
    const int q = lane >> 4;
    const int mr = lane & 15;

    const int m0 = blockIdx.x * 128 + wave * 16;
    int arow = m0 + mr;
    if (arow >= N_NODES) arow = N_NODES - 1;

    f32x4 acc[8] = {};

#pragma unroll
    for (int ks = 0; ks < 4; ++ks) {
        const int k0 = ks * 32 + q * 8;
        const float4* ap = (const float4*)&A_f32[(size_t)arow * DIM + k0];
        float4 a0 = ap[0], a1 = ap[1];
        bf16x8 af;
        af[0] = (__bf16)a0.x; af[1] = (__bf16)a0.y;
        af[2] = (__bf16)a0.z; af[3] = (__bf16)a0.w;
        af[4] = (__bf16)a1.x; af[5] = (__bf16)a1.y;
        af[6] = (__bf16)a1.z; af[7] = (__bf16)a1.w;
#pragma unroll
        for (int nt = 0; nt < 8; ++nt) {
            bf16x8 bfr = *(const bf16x8*)&w_lds[(nt * 16 + mr) * 136 + k0];
            acc[nt] = __builtin_amdgcn_mfma_f32_16x16x32_bf16(af, bfr, acc[nt], 0, 0, 0);
        }
    }

    __syncthreads();                   // all w_lds reads done
    float* lds_f = (float*)w_lds;      // 64 x 132 fp32 buffer
    const int nb = blockIdx.x * 128;

#pragma unroll
    for (int half = 0; half < 2; ++half) {
        if ((wave >> 2) == half) {
            int lw = wave & 3;
#pragma unroll
            for (int nt = 0; nt < 8; ++nt)
#pragma unroll
                for (int r = 0; r < 4; ++r)
                    lds_f[(lw * 16 + q * 4 + r) * 132 + nt * 16 + mr] = acc[nt][r];
        }
        __syncthreads();
        for (int i = t; i < 2048; i += 512) {
            int lr = i >> 5;
            int cg = (i & 31) << 2;
            int grow = nb + half * 64 + lr;
            if (grow < N_NODES) {
                float4 v = *(const float4*)&lds_f[lr * 132 + cg];
                float4 b4 = *(const float4*)&bias[cg];
                bf16x4 o;
                o[0] = (__bf16)fmaxf(v.x + b4.x, 0.f);
                o[1] = (__bf16)fmaxf(v.y + b4.y, 0.f);
                o[2] = (__bf16)fmaxf(v.z + b4.z, 0.f);
                o[3] = (__bf16)fmaxf(v.w + b4.w, 0.f);
                *(bf16x4*)&out_bf16[(size_t)grow * DIM + cg] = o;
            }
        }
        __syncthreads();
    }
}

// ===========================================================================
// K2+K3 FUSED: per 128-row block, each wave aggregates its own 16 MFMA
// A-rows (GIN combine) straight into an LDS A-tile, then the proven
// 512-thread MFMA GEMM2 + bias + relu runs on it.
//  - kills the c round-trip (12.8 MB write + 12.8 MB read) and one launch
//  - gather MLP: 16 bucket slot-lists preloaded (1 coalesced 256B load per
//    node), degrees via scalar loads, 8 row-gathers in flight per step with
//    readlane-broadcast scalar addresses (vs K2's dependent 4-deep chain)
//  - each wave reads only a_lds rows it wrote -> no extra barrier for A
// ===========================================================================
__global__ __launch_bounds__(512, 4) void agg_gemm2_k(
    const __bf16* __restrict__ h,
    const int* __restrict__ cnt,
    const int* __restrict__ bucket,
    const float* __restrict__ eps_p,
    const __bf16* __restrict__ Wb,
    const float* __restrict__ bias,
    float* __restrict__ out)
{
    __shared__ __align__(16) __bf16 lds[2 * 128 * 136];   // 69.6 KB: [W | A]
    __bf16* const w_lds = lds;
    __bf16* const a_lds = lds + 128 * 136;

    const int t = threadIdx.x;

    // ---- stage W tile (issued first; drains under the aggregation phase) ----
    for (int i = t; i < 2048; i += 512) {               // 4 iters, b128 copy
        int n = i >> 4;
        int kk = (i & 15) << 3;
        bf16x8 v = *(const bf16x8*)&Wb[n * DIM + kk];
        *(bf16x8*)&w_lds[n * 136 + kk] = v;
    }

    const int wave = t >> 6;
    const int lane = t & 63;
    const int ch = lane << 1;                           // 2 channels per lane
    const int rowbase = __builtin_amdgcn_readfirstlane(blockIdx.x * 128 + wave * 16);
    const float eps = eps_p[0];

    // ---- preload degrees (scalar) + bucket slot-lists (1 coalesced load/node)
    int degv[16];
    int idxv[16];
#pragma unroll
    for (int i = 0; i < 16; ++i) {
        const int node = rowbase + i;
        const bool ok = node < N_NODES;
        degv[i] = ok ? cnt[node] : 0;
        idxv[i] = ok ? bucket[(node << 6) | lane] : N_NODES;
    }

    // ---- aggregate 16 nodes -> bf16 rows in a_lds ----
#pragma unroll
    for (int i = 0; i < 16; ++i) {
        const int node = rowbase + i;
        const int nd = (node < N_NODES) ? node : N_NODES;
        const int deg = degv[i];
        const unsigned sv = *(const unsigned*)&h[(size_t)nd * DIM + ch];  // self; consumed late
        const int s = (lane < deg) ? idxv[i] : N_NODES;   // lanes >= deg point at zero row
        float ax = 0.f, ay = 0.f;
        // deg <= CAP = 64 and e is a multiple of 8 => e+7 <= 63 always in range
        for (int e = 0; e < deg; e += 8) {
            int s0 = __builtin_amdgcn_readlane(s, e + 0);
            int s1 = __builtin_amdgcn_readlane(s, e + 1);
            int s2 = __builtin_amdgcn_readlane(s, e + 2);
            int s3 = __builtin_amdgcn_readlane(s, e + 3);
            int s4 = __builtin_amdgcn_readlane(s, e + 4);
            int s5 = __builtin_amdgcn_readlane(s, e + 5);
            int s6 = __builtin_amdgcn_readlane(s, e + 6);
            int s7 = __builtin_amdgcn_readlane(s, e + 7);
            unsigned v0 = *(const unsigned*)&h[(size_t)s0 * DIM + ch];
            unsigned v1 = *(const unsigned*)&h[(size_t)s1 * DIM + ch];
            unsigned v2 = *(const unsigned*)&h[(size_t)s2 * DIM + ch];
            unsigned v3 = *(const unsigned*)&h[(size_t)s3 * DIM + ch];
            unsigned v4 = *(const unsigned*)&h[(size_t)s4 * DIM + ch];
            unsigned v5 = *(const unsigned*)&h[(size_t)s5 * DIM + ch];
            unsigned v6 = *(const unsigned*)&h[(size_t)s6 * DIM + ch];
            unsigned v7 = *(const unsigned*)&h[(size_t)s7 * DIM + ch];
            ax += (bflo(v0) + bflo(v1)) + (bflo(v2) + bflo(v3))
                + (bflo(v4) + bflo(v5)) + (bflo(v6) + bflo(v7));
            ay += (bfhi(v0) + bfhi(v1)) + (bfhi(v2) + bfhi(v3))
                + (bfhi(v4) + bfhi(v5)) + (bfhi(v6) + bfhi(v7));
        }
        ax = 1.0f + eps * bflo(sv) + ax;
        ay = 1.0f + eps * bfhi(sv) + ay;
        bf16x2 o; o[0] = (__bf16)ax; o[1] = (__bf16)ay;
        *(bf16x2*)&a_lds[(wave * 16 + i) * 136 + ch] = o;   // own-wave row
    }

    __syncthreads();            // W tile staged by all waves; A rows are own-wave

    const int q = lane >> 4;
    const int mr = lane & 15;

    f32x4 acc[8] = {};

#pragma unroll
    for (int ks = 0; ks < 4; ++ks) {
        const int k0 = ks * 32 + q * 8;
        bf16x8 af = *(const bf16x8*)&a_lds[(wave * 16 + mr) * 136 + k0];
#pragma unroll
        for (int nt = 0; nt < 8; ++nt) {
            bf16x8 bfr = *(const bf16x8*)&w_lds[(nt * 16 + mr) * 136 + k0];
            acc[nt] = __builtin_amdgcn_mfma_f32_16x16x32_bf16(af, bfr, acc[nt], 0, 0, 0);
        }
    }

    __syncthreads();                   // all w_lds/a_lds reads done
    float* lds_f = (float*)lds;        // reuse W half: 64 x 132 fp32 = 33.8 KB
    const int nb = blockIdx.x * 128;

#pragma unroll
    for (int half = 0; half < 2; ++half) {
        if ((wave >> 2) == half) {
            int lw = wave & 3;
#pragma unroll
            for (int nt = 0; nt < 8; ++nt)
#pragma unroll
                for (int r = 0; r < 4; ++r)
                    lds_f[(lw * 16 + q * 4 + r) * 132 + nt * 16 + mr] = acc[nt][r];
        }
        __syncthreads();
        for (int i2 = t; i2 < 2048; i2 += 512) {
            int lr = i2 >> 5;
            int cg = (i2 & 31) << 2;
            int grow = nb + half * 64 + lr;
            if (grow < N_NODES) {
                float4 v = *(const float4*)&lds_f[lr * 132 + cg];
                float4 b4 = *(const float4*)&bias[cg];
                v.x = fmaxf(v.x + b4.x, 0.f);
                v.y = fmaxf(v.y + b4.y, 0.f);
                v.z = fmaxf(v.z + b4.z, 0.f);
                v.w = fmaxf(v.w + b4.w, 0.f);
                *(float4*)&out[(size_t)grow * DIM + cg] = v;
            }
        }
        __syncthreads();
    }
}

extern "C" void kernel_launch(void* const* d_in, const int* in_sizes, int n_in,
                              void* d_out, int out_size, void* d_ws, size_t ws_size,
                              hipStream_t stream) {
    const float* feats = (const float*)d_in[0];
    const int*   src   = (const int*)d_in[1];
    const int*   dst   = (const int*)d_in[2];
    const float* W_f   = (const float*)d_in[3];
    const float* b_f   = (const float*)d_in[4];
    const float* W_phy = (const float*)d_in[5];
    const float* b_phy = (const float*)d_in[6];
    const float* eps   = (const float*)d_in[7];
    float* out = (float*)d_out;

    const size_t HN = (size_t)(N_NODES + 1) * DIM;      // +1 zero row
    __bf16* h   = (__bf16*)d_ws;                        // 12.8 MB
    int* bucket = (int*)(h + HN);                       // 12.8 MB
    int* cnt    = bucket + (size_t)N_NODES * CAP;       // 200 KB
    __bf16* Wb  = (__bf16*)(cnt + N_NODES);             // 32 KB

    const int gblocks = (N_NODES + 127) / 128;          // 391 (K1 gemm part)
    const int fblocks = (N_EDGES / 4 + 511) / 512;      // 306 (K1 fill part)

    hipMemsetAsync(cnt, 0, N_NODES * sizeof(int), stream);

    gemm1_fill_k<<<gblocks + fblocks, 512, 0, stream>>>(
        feats, W_f, b_f, h, src, dst, cnt, bucket, W_phy, Wb, gblocks);

    agg_gemm2_k<<<gblocks, 512, 0, stream>>>(
        h, cnt, bucket, eps, Wb, b_phy, out);
}

// Round 2
// 152.576 us; speedup vs baseline: 1.0394x; 1.0161x over previous
//
#include <hip/hip_runtime.h>

#define N_NODES 50000
#define N_EDGES 625000
#define DIM 128
#define CAP 64            // bucket capacity per node; max degree ~29 (Poisson 12.5)

typedef __bf16 bf16x8 __attribute__((ext_vector_type(8)));
typedef __bf16 bf16x4 __attribute__((ext_vector_type(4)));
typedef __bf16 bf16x2 __attribute__((ext_vector_type(2)));
typedef float f32x4 __attribute__((ext_vector_type(4)));

__device__ __forceinline__ float bflo(unsigned u) { return __uint_as_float(u << 16); }
__device__ __forceinline__ float bfhi(unsigned u) { return __uint_as_float(u & 0xffff0000u); }

// ===========================================================================
// K1: fused [GEMM1 | bucket-CSR fill], 512-thread blocks.
// R2 delta: fill half restructured from 4 edges/thread with interleaved
// atomic->store chains (4 serial L2 round-trips on the critical path) to
// 8 edges/thread with ALL 8 returning atomicAdds issued before ANY bucket
// store -- stores drain with incremental vmcnt waits, overlapping the 8
// atomic latencies into ~1.
// ===========================================================================
__global__ __launch_bounds__(512) void gemm1_fill_k(
    const float* __restrict__ A_f32,
    const float* __restrict__ W,
    const float* __restrict__ bias,
    __bf16* __restrict__ out_bf16,
    const int* __restrict__ src,
    const int* __restrict__ dst,
    int* __restrict__ cnt,
    int* __restrict__ bucket,
    const float* __restrict__ W_phy,
    __bf16* __restrict__ Wb,
    int gemm_blocks)
{
    const int t = threadIdx.x;

    if ((int)blockIdx.x >= gemm_blocks) {
        if ((int)blockIdx.x == gemm_blocks) {
            if (t < 16) {
                bf16x8 z = {};
                *(bf16x8*)&out_bf16[(size_t)N_NODES * DIM + t * 8] = z;
            }
            for (int i = t; i < 4096; i += 512) {
                float4 f = ((const float4*)W_phy)[i];
                bf16x4 pk = { (__bf16)f.x, (__bf16)f.y, (__bf16)f.z, (__bf16)f.w };
                *(bf16x4*)&Wb[i * 4] = pk;
            }
        }
        int idx = ((int)blockIdx.x - gemm_blocks) * 512 + t;
        if (idx < N_EDGES / 8) {                        // 625000 = 8 * 78125
            int4 sa = ((const int4*)src)[idx * 2];
            int4 sb = ((const int4*)src)[idx * 2 + 1];
            int4 da = ((const int4*)dst)[idx * 2];
            int4 db = ((const int4*)dst)[idx * 2 + 1];
            // all returning atomics issued back-to-back (pipelined in L2)
            int p0 = atomicAdd(&cnt[da.x], 1);
            int p1 = atomicAdd(&cnt[da.y], 1);
            int p2 = atomicAdd(&cnt[da.z], 1);
            int p3 = atomicAdd(&cnt[da.w], 1);
            int p4 = atomicAdd(&cnt[db.x], 1);
            int p5 = atomicAdd(&cnt[db.y], 1);
            int p6 = atomicAdd(&cnt[db.z], 1);
            int p7 = atomicAdd(&cnt[db.w], 1);
            // dependent scattered stores drain with incremental vmcnt waits
            bucket[(da.x << 6) + p0] = sa.x;
            bucket[(da.y << 6) + p1] = sa.y;
            bucket[(da.z << 6) + p2] = sa.z;
            bucket[(da.w << 6) + p3] = sa.w;
            bucket[(db.x << 6) + p4] = sb.x;
            bucket[(db.y << 6) + p5] = sb.y;
            bucket[(db.z << 6) + p6] = sb.z;
            bucket[(db.w << 6) + p7] = sb.w;
        }
        return;
    }

    __shared__ __align__(16) __bf16 w_lds[128 * 136];   // 34.8 KB

    for (int i = t; i < 4096; i += 512) {               // 8 iters
        float4 f = ((const float4*)W)[i];
        int n = i >> 5;
        int k = (i & 31) << 2;
        bf16x4 pk = { (__bf16)f.x, (__bf16)f.y, (__bf16)f.z, (__bf16)f.w };
        *(bf16x4*)&w_lds[n * 136 + k] = pk;             // ds_write_b64
    }
    __syncthreads();

    const int wave = t >> 6;           // 0..7
    const int lane = t & 63;
    const int q = lane >> 4;
    const int mr = lane & 15;

    const int m0 = blockIdx.x * 128 + wave * 16;
    int arow = m0 + mr;
    if (arow >= N_NODES) arow = N_NODES - 1;

    f32x4 acc[8] = {};

#pragma unroll
    for (int ks = 0; ks < 4; ++ks) {
        const int k0 = ks * 32 + q * 8;
        const float4* ap = (const float4*)&A_f32[(size_t)arow * DIM + k0];
        float4 a0 = ap[0], a1 = ap[1];
        bf16x8 af;
        af[0] = (__bf16)a0.x; af[1] = (__bf16)a0.y;
        af[2] = (__bf16)a0.z; af[3] = (__bf16)a0.w;
        af[4] = (__bf16)a1.x; af[5] = (__bf16)a1.y;
        af[6] = (__bf16)a1.z; af[7] = (__bf16)a1.w;
#pragma unroll
        for (int nt = 0; nt < 8; ++nt) {
            bf16x8 bfr = *(const bf16x8*)&w_lds[(nt * 16 + mr) * 136 + k0];
            acc[nt] = __builtin_amdgcn_mfma_f32_16x16x32_bf16(af, bfr, acc[nt], 0, 0, 0);
        }
    }

    __syncthreads();                   // all w_lds reads done
    float* lds_f = (float*)w_lds;      // 64 x 132 fp32 buffer
    const int nb = blockIdx.x * 128;

#pragma unroll
    for (int half = 0; half < 2; ++half) {
        if ((wave >> 2) == half) {
            int lw = wave & 3;
#pragma unroll
            for (int nt = 0; nt < 8; ++nt)
#pragma unroll
                for (int r = 0; r < 4; ++r)
                    lds_f[(lw * 16 + q * 4 + r) * 132 + nt * 16 + mr] = acc[nt][r];
        }
        __syncthreads();
        for (int i = t; i < 2048; i += 512) {
            int lr = i >> 5;
            int cg = (i & 31) << 2;
            int grow = nb + half * 64 + lr;
            if (grow < N_NODES) {
                float4 v = *(const float4*)&lds_f[lr * 132 + cg];
                float4 b4 = *(const float4*)&bias[cg];
                bf16x4 o;
                o[0] = (__bf16)fmaxf(v.x + b4.x, 0.f);
                o[1] = (__bf16)fmaxf(v.y + b4.y, 0.f);
                o[2] = (__bf16)fmaxf(v.z + b4.z, 0.f);
                o[3] = (__bf16)fmaxf(v.w + b4.w, 0.f);
                *(bf16x4*)&out_bf16[(size_t)grow * DIM + cg] = o;
            }
        }
        __syncthreads();
    }
}

// ===========================================================================
// K2+K3 FUSED (unchanged this round): per 128-row block, each wave
// aggregates its own 16 MFMA A-rows straight into an LDS A-tile, then the
// 512-thread MFMA GEMM2 + bias + relu runs on it. ~19-20 us, near the
// 160 MB L3-gather floor.
// ===========================================================================
__global__ __launch_bounds__(512, 4) void agg_gemm2_k(
    const __bf16* __restrict__ h,
    const int* __restrict__ cnt,
    const int* __restrict__ bucket,
    const float* __restrict__ eps_p,
    const __bf16* __restrict__ Wb,
    const float* __restrict__ bias,
    float* __restrict__ out)
{
    __shared__ __align__(16) __bf16 lds[2 * 128 * 136];   // 69.6 KB: [W | A]
    __bf16* const w_lds = lds;
    __bf16* const a_lds = lds + 128 * 136;

    const int t = threadIdx.x;

    // ---- stage W tile (issued first; drains under the aggregation phase) ----
    for (int i = t; i < 2048; i += 512) {               // 4 iters, b128 copy
        int n = i >> 4;
        int kk = (i & 15) << 3;
        bf16x8 v = *(const bf16x8*)&Wb[n * DIM + kk];
        *(bf16x8*)&w_lds[n * 136 + kk] = v;
    }

    const int wave = t >> 6;
    const int lane = t & 63;
    const int ch = lane << 1;                           // 2 channels per lane
    const int rowbase = __builtin_amdgcn_readfirstlane(blockIdx.x * 128 + wave * 16);
    const float eps = eps_p[0];

    // ---- preload degrees (scalar) + bucket slot-lists (1 coalesced load/node)
    int degv[16];
    int idxv[16];
#pragma unroll
    for (int i = 0; i < 16; ++i) {
        const int node = rowbase + i;
        const bool ok = node < N_NODES;
        degv[i] = ok ? cnt[node] : 0;
        idxv[i] = ok ? bucket[(node << 6) | lane] : N_NODES;
    }

    // ---- aggregate 16 nodes -> bf16 rows in a_lds ----
#pragma unroll
    for (int i = 0; i < 16; ++i) {
        const int node = rowbase + i;
        const int nd = (node < N_NODES) ? node : N_NODES;
        const int deg = degv[i];
        const unsigned sv = *(const unsigned*)&h[(size_t)nd * DIM + ch];  // self; consumed late
        const int s = (lane < deg) ? idxv[i] : N_NODES;   // lanes >= deg point at zero row
        float ax = 0.f, ay = 0.f;
        // deg <= CAP = 64 and e is a multiple of 8 => e+7 <= 63 always in range
        for (int e = 0; e < deg; e += 8) {
            int s0 = __builtin_amdgcn_readlane(s, e + 0);
            int s1 = __builtin_amdgcn_readlane(s, e + 1);
            int s2 = __builtin_amdgcn_readlane(s, e + 2);
            int s3 = __builtin_amdgcn_readlane(s, e + 3);
            int s4 = __builtin_amdgcn_readlane(s, e + 4);
            int s5 = __builtin_amdgcn_readlane(s, e + 5);
            int s6 = __builtin_amdgcn_readlane(s, e + 6);
            int s7 = __builtin_amdgcn_readlane(s, e + 7);
            unsigned v0 = *(const unsigned*)&h[(size_t)s0 * DIM + ch];
            unsigned v1 = *(const unsigned*)&h[(size_t)s1 * DIM + ch];
            unsigned v2 = *(const unsigned*)&h[(size_t)s2 * DIM + ch];
            unsigned v3 = *(const unsigned*)&h[(size_t)s3 * DIM + ch];
            unsigned v4 = *(const unsigned*)&h[(size_t)s4 * DIM + ch];
            unsigned v5 = *(const unsigned*)&h[(size_t)s5 * DIM + ch];
            unsigned v6 = *(const unsigned*)&h[(size_t)s6 * DIM + ch];
            unsigned v7 = *(const unsigned*)&h[(size_t)s7 * DIM + ch];
            ax += (bflo(v0) + bflo(v1)) + (bflo(v2) + bflo(v3))
                + (bflo(v4) + bflo(v5)) + (bflo(v6) + bflo(v7));
            ay += (bfhi(v0) + bfhi(v1)) + (bfhi(v2) + bfhi(v3))
                + (bfhi(v4) + bfhi(v5)) + (bfhi(v6) + bfhi(v7));
        }
        ax = 1.0f + eps * bflo(sv) + ax;
        ay = 1.0f + eps * bfhi(sv) + ay;
        bf16x2 o; o[0] = (__bf16)ax; o[1] = (__bf16)ay;
        *(bf16x2*)&a_lds[(wave * 16 + i) * 136 + ch] = o;   // own-wave row
    }

    __syncthreads();            // W tile staged by all waves; A rows are own-wave

    const int q = lane >> 4;
    const int mr = lane & 15;

    f32x4 acc[8] = {};

#pragma unroll
    for (int ks = 0; ks < 4; ++ks) {
        const int k0 = ks * 32 + q * 8;
        bf16x8 af = *(const bf16x8*)&a_lds[(wave * 16 + mr) * 136 + k0];
#pragma unroll
        for (int nt = 0; nt < 8; ++nt) {
            bf16x8 bfr = *(const bf16x8*)&w_lds[(nt * 16 + mr) * 136 + k0];
            acc[nt] = __builtin_amdgcn_mfma_f32_16x16x32_bf16(af, bfr, acc[nt], 0, 0, 0);
        }
    }

    __syncthreads();                   // all w_lds/a_lds reads done
    float* lds_f = (float*)lds;        // reuse W half: 64 x 132 fp32 = 33.8 KB
    const int nb = blockIdx.x * 128;

#pragma unroll
    for (int half = 0; half < 2; ++half) {
        if ((wave >> 2) == half) {
            int lw = wave & 3;
#pragma unroll
            for (int nt = 0; nt < 8; ++nt)
#pragma unroll
                for (int r = 0; r < 4; ++r)
                    lds_f[(lw * 16 + q * 4 + r) * 132 + nt * 16 + mr] = acc[nt][r];
        }
        __syncthreads();
        for (int i2 = t; i2 < 2048; i2 += 512) {
            int lr = i2 >> 5;
            int cg = (i2 & 31) << 2;
            int grow = nb + half * 64 + lr;
            if (grow < N_NODES) {
                float4 v = *(const float4*)&lds_f[lr * 132 + cg];
                float4 b4 = *(const float4*)&bias[cg];
                v.x = fmaxf(v.x + b4.x, 0.f);
                v.y = fmaxf(v.y + b4.y, 0.f);
                v.z = fmaxf(v.z + b4.z, 0.f);
                v.w = fmaxf(v.w + b4.w, 0.f);
                *(float4*)&out[(size_t)grow * DIM + cg] = v;
            }
        }
        __syncthreads();
    }
}

extern "C" void kernel_launch(void* const* d_in, const int* in_sizes, int n_in,
                              void* d_out, int out_size, void* d_ws, size_t ws_size,
                              hipStream_t stream) {
    const float* feats = (const float*)d_in[0];
    const int*   src   = (const int*)d_in[1];
    const int*   dst   = (const int*)d_in[2];
    const float* W_f   = (const float*)d_in[3];
    const float* b_f   = (const float*)d_in[4];
    const float* W_phy = (const float*)d_in[5];
    const float* b_phy = (const float*)d_in[6];
    const float* eps   = (const float*)d_in[7];
    float* out = (float*)d_out;

    const size_t HN = (size_t)(N_NODES + 1) * DIM;      // +1 zero row
    __bf16* h   = (__bf16*)d_ws;                        // 12.8 MB
    int* bucket = (int*)(h + HN);                       // 12.8 MB
    int* cnt    = bucket + (size_t)N_NODES * CAP;       // 200 KB
    __bf16* Wb  = (__bf16*)(cnt + N_NODES);             // 32 KB

    const int gblocks = (N_NODES + 127) / 128;          // 391 (K1 gemm part)
    const int fblocks = (N_EDGES / 8 + 511) / 512;      // 153 (K1 fill part, 8 edges/thread)

    hipMemsetAsync(cnt, 0, N_NODES * sizeof(int), stream);

    gemm1_fill_k<<<gblocks + fblocks, 512, 0, stream>>>(
        feats, W_f, b_f, h, src, dst, cnt, bucket, W_phy, Wb, gblocks);

    agg_gemm2_k<<<gblocks, 512, 0, stream>>>(
        h, cnt, bucket, eps, Wb, b_phy, out);
}